// Round 24
// baseline (740.676 us; speedup 1.0000x reference)
//
#include <hip/hip_runtime.h>
#include <hip/hip_bf16.h>
#include <stdint.h>

#define B_  2048
#define D_  512
#define M_  32768
#define H_  4
#define HD_ 128
#define K_  64
#define MS_ 8
#define SLICE_ (M_ / MS_)
#define CH_ 128
#define ROWS_ 32
#define T_  8

typedef __attribute__((ext_vector_type(8))) short short8;
typedef __attribute__((ext_vector_type(4))) float float4v;
typedef __attribute__((ext_vector_type(2))) float float2v;

__device__ __forceinline__ ushort f2bf_rne(float f) {
  union { float f; unsigned u; } c; c.f = f;
  unsigned r = (c.u + 0x7fffu + ((c.u >> 16) & 1u)) >> 16;
  return (ushort)r;
}
__device__ __forceinline__ float bf2f(ushort u) {
  union { unsigned u; float f; } c; c.u = ((unsigned)u) << 16;
  return c.f;
}
__device__ __forceinline__ uint32_t make_key(float s, int inv) {
  union { float f; unsigned u; } c; c.f = s;
  unsigned m = c.u ^ ((unsigned)(((int)c.u) >> 31) | 0x80000000u);
  return ((m >> 16) << 13) | (unsigned)inv;
}
__device__ __forceinline__ unsigned sortflip32(float s) {
  union { float f; unsigned u; } c; c.f = s;
  return c.u ^ ((unsigned)(((int)c.u) >> 31) | 0x80000000u);
}

// ---------------------------------------------------------------------------
// fp32 GEMM, BM=128 tile (K-projection).  SELECTION-CRITICAL: exact fp32
// sequential-k accumulation (R6+R19 law).  LDS double-buffer (R20).
// ---------------------------------------------------------------------------
__global__ __launch_bounds__(256) void gemm_nt_bias(
    const float* __restrict__ X, const float* __restrict__ W,
    const float* __restrict__ bias, float* __restrict__ C, int N,
    ushort* __restrict__ Cbf) {
  __shared__ float As[2][16][132];
  __shared__ float Bs[2][16][132];
  const int t  = threadIdx.x;
  const int tx = t & 15, ty = t >> 4;
  const int rowbase = blockIdx.x * 128;
  const int colbase = blockIdx.y * 128;
  float2v acc2[8][4];
  #pragma unroll
  for (int i = 0; i < 8; ++i)
    #pragma unroll
    for (int j = 0; j < 4; ++j) acc2[i][j] = (float2v){0.f, 0.f};

  float4 va[2], vw[2];
  auto gload = [&](int k0) {
    #pragma unroll
    for (int i = 0; i < 2; ++i) {
      int idx = t + i * 256;
      int r = idx >> 2, kq = idx & 3;
      va[i] = *(const float4*)&X[(size_t)(rowbase + r) * 512 + k0 + kq * 4];
      vw[i] = *(const float4*)&W[(size_t)(colbase + r) * 512 + k0 + kq * 4];
    }
  };
  auto sstore = [&](int buf) {
    #pragma unroll
    for (int i = 0; i < 2; ++i) {
      int idx = t + i * 256;
      int r = idx >> 2, kq = idx & 3;
      As[buf][kq*4+0][r] = va[i].x; As[buf][kq*4+1][r] = va[i].y;
      As[buf][kq*4+2][r] = va[i].z; As[buf][kq*4+3][r] = va[i].w;
      Bs[buf][kq*4+0][r] = vw[i].x; Bs[buf][kq*4+1][r] = vw[i].y;
      Bs[buf][kq*4+2][r] = vw[i].z; Bs[buf][kq*4+3][r] = vw[i].w;
    }
  };

  gload(0);
  sstore(0);
  __syncthreads();
  for (int k0 = 0; k0 < 512; k0 += 16) {
    const int cur = (k0 >> 4) & 1;
    const bool more = (k0 + 16) < 512;
    if (more) gload(k0 + 16);
    #pragma unroll
    for (int k = 0; k < 16; ++k) {
      float a[8], b[8];
      *(float4*)&a[0] = *(const float4*)&As[cur][k][ty*8];
      *(float4*)&a[4] = *(const float4*)&As[cur][k][ty*8+4];
      *(float4*)&b[0] = *(const float4*)&Bs[cur][k][tx*8];
      *(float4*)&b[4] = *(const float4*)&Bs[cur][k][tx*8+4];
      const float2v* a2 = (const float2v*)a;
      const float2v* b2 = (const float2v*)b;
      #pragma unroll
      for (int i2 = 0; i2 < 4; ++i2) {
        #pragma unroll
        for (int j = 0; j < 4; ++j) {
          asm("v_pk_fma_f32 %0, %1, %2, %0 op_sel:[0,0,0] op_sel_hi:[0,1,1]"
              : "+v"(acc2[2*i2][j]) : "v"(a2[i2]), "v"(b2[j]));
          asm("v_pk_fma_f32 %0, %1, %2, %0 op_sel:[1,0,0] op_sel_hi:[1,1,1]"
              : "+v"(acc2[2*i2+1][j]) : "v"(a2[i2]), "v"(b2[j]));
        }
      }
    }
    if (more) sstore(cur ^ 1);
    __syncthreads();
  }
  const int hh = colbase >> 7;
  #pragma unroll
  for (int i = 0; i < 8; ++i) {
    size_t r = (size_t)(rowbase + ty*8 + i);
    #pragma unroll
    for (int j4 = 0; j4 < 2; ++j4) {
      int c = colbase + tx*8 + j4*4;
      float4 bv = *(const float4*)&bias[c];
      float4 o;
      o.x = acc2[i][j4*2+0][0] + bv.x;
      o.y = acc2[i][j4*2+0][1] + bv.y;
      o.z = acc2[i][j4*2+1][0] + bv.z;
      o.w = acc2[i][j4*2+1][1] + bv.w;
      *(float4*)&C[r * 512 + c] = o;
      if (Cbf) {
        ushort u[4] __attribute__((aligned(8)));
        u[0] = f2bf_rne(o.x); u[1] = f2bf_rne(o.y);
        u[2] = f2bf_rne(o.z); u[3] = f2bf_rne(o.w);
        const int dd = tx * 8 + j4 * 4;
        *(ushort4*)&Cbf[((size_t)hh * N + r) * 128 + dd] = *(ushort4*)u;
      }
    }
  }
}

// ---------------------------------------------------------------------------
// fp32 GEMM, BM=64 tile — B_-row projections (Q, out).  fp32 (R6).
// ---------------------------------------------------------------------------
__global__ __launch_bounds__(256) void gemm_nt_bias64(
    const float* __restrict__ X, const float* __restrict__ W,
    const float* __restrict__ bias, float* __restrict__ C, int N,
    ushort* __restrict__ Cbf) {
  __shared__ float As[16][68];
  __shared__ float Bs[16][132];
  const int t  = threadIdx.x;
  const int tx = t & 15, ty = t >> 4;
  const int rowbase = blockIdx.x * 64;
  const int colbase = blockIdx.y * 128;
  float acc[4][8];
  #pragma unroll
  for (int i = 0; i < 4; ++i)
    #pragma unroll
    for (int j = 0; j < 8; ++j) acc[i][j] = 0.f;

  float4 va, vw[2];
  auto gload = [&](int k0) {
    { int r = t >> 2, kq = t & 3;
      va = *(const float4*)&X[(size_t)(rowbase + r) * 512 + k0 + kq * 4]; }
    #pragma unroll
    for (int i = 0; i < 2; ++i) {
      int idx = t + i * 256;
      int r = idx >> 2, kq = idx & 3;
      vw[i] = *(const float4*)&W[(size_t)(colbase + r) * 512 + k0 + kq * 4];
    }
  };
  auto sstore = [&]() {
    { int r = t >> 2, kq = t & 3;
      As[kq*4+0][r] = va.x; As[kq*4+1][r] = va.y;
      As[kq*4+2][r] = va.z; As[kq*4+3][r] = va.w; }
    #pragma unroll
    for (int i = 0; i < 2; ++i) {
      int idx = t + i * 256;
      int r = idx >> 2, kq = idx & 3;
      Bs[kq*4+0][r] = vw[i].x; Bs[kq*4+1][r] = vw[i].y;
      Bs[kq*4+2][r] = vw[i].z; Bs[kq*4+3][r] = vw[i].w;
    }
  };

  gload(0);
  for (int k0 = 0; k0 < 512; k0 += 16) {
    sstore();
    __syncthreads();
    if (k0 + 16 < 512) gload(k0 + 16);
    #pragma unroll
    for (int k = 0; k < 16; ++k) {
      float a[4], b[8];
      *(float4*)&a[0] = *(const float4*)&As[k][ty*4];
      *(float4*)&b[0] = *(const float4*)&Bs[k][tx*8];
      *(float4*)&b[4] = *(const float4*)&Bs[k][tx*8+4];
      #pragma unroll
      for (int i = 0; i < 4; ++i)
        #pragma unroll
        for (int j = 0; j < 8; ++j)
          acc[i][j] = fmaf(a[i], b[j], acc[i][j]);
    }
    __syncthreads();
  }
  const int hh = colbase >> 7;
  #pragma unroll
  for (int i = 0; i < 4; ++i) {
    size_t r = (size_t)(rowbase + ty*4 + i);
    #pragma unroll
    for (int j4 = 0; j4 < 2; ++j4) {
      int c = colbase + tx*8 + j4*4;
      float4 bv = *(const float4*)&bias[c];
      float4 o;
      o.x = acc[i][j4*4+0] + bv.x;
      o.y = acc[i][j4*4+1] + bv.y;
      o.z = acc[i][j4*4+2] + bv.z;
      o.w = acc[i][j4*4+3] + bv.w;
      *(float4*)&C[r * 512 + c] = o;
      if (Cbf) {
        ushort u[4] __attribute__((aligned(8)));
        u[0] = f2bf_rne(o.x); u[1] = f2bf_rne(o.y);
        u[2] = f2bf_rne(o.z); u[3] = f2bf_rne(o.w);
        const int dd = tx * 8 + j4 * 4;
        *(ushort4*)&Cbf[((size_t)hh * N + r) * 128 + dd] = *(ushort4*)u;
      }
    }
  }
}

// ---------------------------------------------------------------------------
// Convert fp32 weight -> bf16 (single, RNE).  V projection only.
// ---------------------------------------------------------------------------
__global__ __launch_bounds__(256) void convert_w1(
    const float* __restrict__ W, ushort* __restrict__ W1) {
  const int i = (blockIdx.x * 256 + threadIdx.x) * 4;
  float4 v = *(const float4*)&W[i];
  ushort u1[4] __attribute__((aligned(8)));
  u1[0] = f2bf_rne(v.x); u1[1] = f2bf_rne(v.y);
  u1[2] = f2bf_rne(v.z); u1[3] = f2bf_rne(v.w);
  *(ushort4*)&W1[i] = *(ushort4*)u1;
}

// ---------------------------------------------------------------------------
// Single-bf16 MFMA GEMM — V projection (R22; V enters output linearly).
// ---------------------------------------------------------------------------
__global__ __launch_bounds__(256, 4) void gemm_bf16_nt(
    const float* __restrict__ X, const ushort* __restrict__ W1,
    const float* __restrict__ bias, float* __restrict__ C, int N) {
  const int t = threadIdx.x, w = t >> 6, lane = t & 63;
  const int l15 = lane & 15, l4 = lane >> 4;
  const int nb = blockIdx.x * 128 + w * 32;
  const int ob = blockIdx.y * 128;
  const short* w1s = (const short*)W1;

  float4v acc[2][8];
  #pragma unroll
  for (int nt = 0; nt < 2; ++nt)
    #pragma unroll
    for (int ot = 0; ot < 8; ++ot) acc[nt][ot] = (float4v){0.f, 0.f, 0.f, 0.f};

  for (int ks = 0; ks < 16; ++ks) {
    short8 x1[2];
    #pragma unroll
    for (int nt = 0; nt < 2; ++nt) {
      const float* xp = X + (size_t)(nb + nt * 16 + l15) * 512 + ks * 32 + l4 * 8;
      float xv[8];
      *(float4*)&xv[0] = *(const float4*)xp;
      *(float4*)&xv[4] = *(const float4*)(xp + 4);
      #pragma unroll
      for (int j = 0; j < 8; ++j)
        ((ushort*)&x1[nt])[j] = f2bf_rne(xv[j]);
    }
    #pragma unroll
    for (int ot = 0; ot < 8; ++ot) {
      const size_t wo = (size_t)(ob + ot * 16 + l15) * 512 + ks * 32 + l4 * 8;
      short8 wf1 = *(const short8*)(w1s + wo);
      #pragma unroll
      for (int nt = 0; nt < 2; ++nt)
        acc[nt][ot] = __builtin_amdgcn_mfma_f32_16x16x32_bf16(wf1, x1[nt], acc[nt][ot], 0, 0, 0);
    }
  }

  #pragma unroll
  for (int nt = 0; nt < 2; ++nt) {
    const size_t row = (size_t)(nb + nt * 16 + l15);
    #pragma unroll
    for (int ot = 0; ot < 8; ++ot) {
      const int col = ob + ot * 16 + l4 * 4;
      float4 bv = *(const float4*)&bias[col];
      float4 o;
      o.x = acc[nt][ot][0] + bv.x;
      o.y = acc[nt][ot][1] + bv.y;
      o.z = acc[nt][ot][2] + bv.z;
      o.w = acc[nt][ot][3] + bv.w;
      *(float4*)&C[row * 512 + col] = o;
    }
  }
}

// ---------------------------------------------------------------------------
// Pass 1: bf16 MFMA scores + selection in MFMA output layout.
// R24: 2-DEEP asm load pipeline.  R18's 1-deep pipeline (vmcnt(8), one
// compute-phase of cover ~500-900cy) left VALUBusy at 39% — loaded L2
// latency under 2048 concurrent WGs exceeds one phase.  Now 4 buffers,
// 32 loads in flight, counted vmcnt(24)/vmcnt(16) peel the oldest chunk;
// role-alternating unroll-by-4 (no register moves); exact-count epilogue
// (no OOB issues).  launch_bounds(256,2) for the ~210-VGPR budget.
// Selection math identical (absmax must stay bit-equal).
// ---------------------------------------------------------------------------
__global__ __launch_bounds__(256, 2) void scores_topk_ll(
    const ushort* __restrict__ Qbf, const ushort* __restrict__ Kbf,
    uint32_t* __restrict__ tkp) {
  const int t = threadIdx.x, w = t >> 6, lane = t & 63;
  const int l   = blockIdx.x;
  const int xcd = l & 7;
  const int i2  = l >> 3;
  const int s   = xcd + 8 * (i2 >> 6);
  const int h   = s >> 3, z = s & 7;
  const int rowbase = (i2 & 63) * ROWS_;
  const int mbase = z * SLICE_;
  const int l15 = lane & 15, l4 = lane >> 4;

  short8 qf0[4], qf1[4];
  {
    const short* Q0 = (const short*)Qbf +
        ((size_t)h * B_ + rowbase + l15) * 128 + l4 * 8;
    const short* Q1 = (const short*)Qbf +
        ((size_t)h * B_ + rowbase + 16 + l15) * 128 + l4 * 8;
    #pragma unroll
    for (int ks = 0; ks < 4; ++ks) {
      qf0[ks] = *(const short8*)(Q0 + ks * 32);
      qf1[ks] = *(const short8*)(Q1 + ks * 32);
    }
  }

  const short* Kh = (const short*)Kbf + (size_t)h * M_ * 128;

  uint32_t kt0[T_], kt1[T_];
  #pragma unroll
  for (int j = 0; j < T_; ++j) { kt0[j] = 0u; kt1[j] = 0u; }

  auto ins = [&](uint32_t c, uint32_t* kt) {
    uint32_t prev = kt[0];
    kt[0] = (kt[0] >= c) ? kt[0] : c;
    #pragma unroll
    for (int i = 1; i < T_; ++i) {
      uint32_t cur = kt[i];
      uint32_t nv;
      asm("v_med3_u32 %0, %1, %2, %3" : "=v"(nv) : "v"(prev), "v"(cur), "v"(c));
      kt[i] = nv;
      prev = cur;
    }
  };

  uint64_t adr[8];
  #pragma unroll
  for (int tt = 0; tt < 2; ++tt)
    #pragma unroll
    for (int ks = 0; ks < 4; ++ks)
      adr[tt * 4 + ks] = (uint64_t)(Kh +
          (size_t)(mbase + 32 * w + 16 * tt + l15) * 128 + ks * 32 + l4 * 8);

  short8 bA[8], bB[8], bC[8], bD[8];
  auto issue = [&](short8 (&buf)[8]) {
    #pragma unroll
    for (int i = 0; i < 8; ++i) {
      asm volatile("global_load_dwordx4 %0, %1, off"
                   : "=&v"(buf[i]) : "v"(adr[i]));
      adr[i] += (uint64_t)(CH_ * 128 * 2);   // 32 KB to next chunk
    }
  };
  auto compute = [&](int ch, short8 (&buf)[8]) {
    #pragma unroll
    for (int tt = 0; tt < 2; ++tt) {
      const int inv0 = SLICE_ - 1 - (ch * CH_ + 32 * w + 16 * tt + 4 * l4);
      float4v a0 = {0.f, 0.f, 0.f, 0.f};
      float4v a1 = {0.f, 0.f, 0.f, 0.f};
      #pragma unroll
      for (int ks = 0; ks < 4; ++ks) {
        a0 = __builtin_amdgcn_mfma_f32_16x16x32_bf16(buf[tt * 4 + ks], qf0[ks], a0, 0, 0, 0);
        a1 = __builtin_amdgcn_mfma_f32_16x16x32_bf16(buf[tt * 4 + ks], qf1[ks], a1, 0, 0, 0);
      }
      #pragma unroll
      for (int reg = 0; reg < 4; ++reg) ins(make_key(a0[reg], inv0 - reg), kt0);
      #pragma unroll
      for (int reg = 0; reg < 4; ++reg) ins(make_key(a1[reg], inv0 - reg), kt1);
    }
  };

  // 2-deep pipeline over NCH=32 chunks: main loop covers chunks 0..27
  // (issuing through 29), epilogue finishes 28..31 with exact drains.
  issue(bA);                 // chunk 0
  issue(bB);                 // chunk 1
  for (int ch = 0; ch < 28; ch += 4) {
    issue(bC);               // ch+2
    issue(bD);               // ch+3   -> 32 loads outstanding
    asm volatile("s_waitcnt vmcnt(24)" ::: "memory");  // bA (ch) done
    __builtin_amdgcn_sched_barrier(0);
    compute(ch, bA);
    asm volatile("s_waitcnt vmcnt(16)" ::: "memory");  // bB (ch+1) done
    __builtin_amdgcn_sched_barrier(0);
    compute(ch + 1, bB);
    issue(bA);               // ch+4
    issue(bB);               // ch+5   -> 32 outstanding again
    asm volatile("s_waitcnt vmcnt(24)" ::: "memory");  // bC (ch+2) done
    __builtin_amdgcn_sched_barrier(0);
    compute(ch + 2, bC);
    asm volatile("s_waitcnt vmcnt(16)" ::: "memory");  // bD (ch+3) done
    __builtin_amdgcn_sched_barrier(0);
    compute(ch + 3, bD);
  }
  // in flight: bA=28, bB=29.  Issue the final two chunks and drain.
  issue(bC);                 // 30
  issue(bD);                 // 31
  asm volatile("s_waitcnt vmcnt(24)" ::: "memory");
  __builtin_amdgcn_sched_barrier(0);
  compute(28, bA);
  asm volatile("s_waitcnt vmcnt(16)" ::: "memory");
  __builtin_amdgcn_sched_barrier(0);
  compute(29, bB);
  asm volatile("s_waitcnt vmcnt(8)" ::: "memory");
  __builtin_amdgcn_sched_barrier(0);
  compute(30, bC);
  asm volatile("s_waitcnt vmcnt(0)" ::: "memory");
  __builtin_amdgcn_sched_barrier(0);
  compute(31, bD);

  const int id = w * 4 + l4;
  const size_t base0 =
      ((((size_t)(rowbase + l15)) * H_ + h) * MS_ + z) * (16 * T_) + (size_t)id * T_;
  const size_t base1 =
      ((((size_t)(rowbase + 16 + l15)) * H_ + h) * MS_ + z) * (16 * T_) + (size_t)id * T_;
  #pragma unroll
  for (int j = 0; j < T_; ++j) {
    tkp[base0 + j] = kt0[j];
    tkp[base1 + j] = kt1[j];
  }
}

// ---------------------------------------------------------------------------
// Merge: per (b,h), 1024 pooled keys -> threshold set (theta with -(1<<16)
// margin), compacted indices into tki.  Runs before V-proj clobbers tkp.
// ---------------------------------------------------------------------------
__global__ __launch_bounds__(256) void topk_select(
    const uint32_t* __restrict__ tkp, int* __restrict__ tki) {
  __shared__ unsigned h1[256];
  __shared__ unsigned h2[256];
  __shared__ unsigned bstar, cstar, nabove;
  __shared__ int ocnt;
  __shared__ int outi[256];
  const int t = threadIdx.x;
  const int bh = blockIdx.x;
  const uint32_t* src = tkp + (size_t)bh * (MS_ * 16 * T_);
  uint32_t k[4];
  #pragma unroll
  for (int j = 0; j < 4; ++j) k[j] = src[j * 256 + t];
  h1[t] = 0; h2[t] = 0;
  if (t == 0) ocnt = 0;
  __syncthreads();
  #pragma unroll
  for (int j = 0; j < 4; ++j) atomicAdd(&h1[k[j] >> 24], 1u);
  __syncthreads();
  unsigned v = h1[t];
  for (int d = 1; d < 256; d <<= 1) {
    unsigned o = (t + d < 256) ? h1[t + d] : 0u;
    __syncthreads();
    v += o; h1[t] = v;
    __syncthreads();
  }
  if (h1[t] >= 64u && (t == 255 || h1[t + 1] < 64u)) {
    bstar = (unsigned)t; nabove = (t == 255) ? 0u : h1[t + 1];
  }
  __syncthreads();
  const unsigned bs = bstar, na = nabove;
  #pragma unroll
  for (int j = 0; j < 4; ++j)
    if ((k[j] >> 24) == bs) atomicAdd(&h2[(k[j] >> 16) & 0xFFu], 1u);
  __syncthreads();
  v = h2[t];
  for (int d = 1; d < 256; d <<= 1) {
    unsigned o = (t + d < 256) ? h2[t + d] : 0u;
    __syncthreads();
    v += o; h2[t] = v;
    __syncthreads();
  }
  if (na + h2[t] >= 64u && (t == 255 || na + h2[t + 1] < 64u)) cstar = (unsigned)t;
  __syncthreads();
  const uint32_t theta = ((((bs << 8) | cstar) << 16)) - 65536u;
  #pragma unroll
  for (int j = 0; j < 4; ++j) {
    if (k[j] >= theta) {
      int p = atomicAdd(&ocnt, 1);
      if (p < 256) {
        const int pos = j * 256 + t;
        const int z = pos >> 7;
        const int ci = (SLICE_ - 1) - (int)(k[j] & 0xFFFu);
        outi[p] = (z << 12) | ci;
      }
    }
  }
  __syncthreads();
  int n = ocnt; if (n > 256) n = 256;
  if (t >= n) outi[t] = -(t + 1);
  __syncthreads();
  tki[(size_t)bh * 256 + t] = outi[t];
}

// ---------------------------------------------------------------------------
// Pass 2: exact fp32 rescore (padded slots skip gathers) + rank-based exact
// top-64 + softmax + V-gather.
// ---------------------------------------------------------------------------
__global__ __launch_bounds__(256) void rescore_attend(
    const float* __restrict__ Qp, const float* __restrict__ Kp,
    const float* __restrict__ Vp, const int* __restrict__ tki,
    float* __restrict__ att) {
  __shared__ float q_[128];
  __shared__ float s_[256];
  __shared__ int   i_[256];
  __shared__ unsigned long long sk_[256];
  __shared__ float wsm[64];
  __shared__ int   widx[64];
  __shared__ float smax_s;
  const int bh = blockIdx.x, b = bh >> 2, h = bh & 3;
  const int t = threadIdx.x, w = t >> 6, lane = t & 63;
  const float SCALE = 0.08838834764831843f;

  if (t < 32) *(float4*)&q_[t * 4] = *(const float4*)&Qp[(size_t)b * 512 + h * 128 + t * 4];
  i_[t] = tki[(size_t)bh * 256 + t];
  __syncthreads();

  const int o = lane >> 3, il = lane & 7;
  #pragma unroll 2
  for (int p = 0; p < 8; ++p) {
    const int j = w * 64 + p * 8 + o;
    const int idx = i_[j];
    if (idx >= 0) {
      const float* kr = Kp + (size_t)idx * 512 + h * 128;
      float part = 0.f;
      #pragma unroll
      for (int u = 0; u < 4; ++u) {
        const int f = il + u * 8;
        float4 kv = *(const float4*)&kr[f * 4];
        float4 qv = *(const float4*)&q_[f * 4];
        part += kv.x * qv.x + kv.y * qv.y + kv.z * qv.z + kv.w * qv.w;
      }
      part += __shfl_xor(part, 1);
      part += __shfl_xor(part, 2);
      part += __shfl_xor(part, 4);
      if (il == 0) s_[j] = part * SCALE;
    } else {
      if (il == 0) s_[j] = -3.0e38f;
    }
  }
  __syncthreads();

  sk_[t] = ((unsigned long long)sortflip32(s_[t]) << 32) |
           (unsigned)(~(unsigned)i_[t]);
  __syncthreads();
  const unsigned long long myk = sk_[t];
  int rank = 0;
  #pragma unroll 8
  for (int j = 0; j < 256; ++j) rank += (sk_[j] > myk) ? 1 : 0;
  const bool sel = (rank < 64);
  if (rank == 0) smax_s = s_[t];
  __syncthreads();
  if (sel) {
    wsm[rank]  = expf(s_[t] - smax_s);
    widx[rank] = i_[t];
  }
  __syncthreads();
  if (t < 64) {
    float zz = wsm[t];
    #pragma unroll
    for (int off = 32; off; off >>= 1) zz += __shfl_xor(zz, off);
    wsm[t] = wsm[t] / zz;
  }
  __syncthreads();

  if (t < 128) {
    float a = 0.f;
    #pragma unroll 4
    for (int k2 = 0; k2 < 64; ++k2)
      a = fmaf(wsm[k2], Vp[(size_t)widx[k2] * 512 + h * 128 + t], a);
    att[(size_t)b * 512 + h * 128 + t] = a;
  }
}

// ---------------------------------------------------------------------------
extern "C" void kernel_launch(void* const* d_in, const int* in_sizes, int n_in,
                              void* d_out, int out_size, void* d_ws, size_t ws_size,
                              hipStream_t stream) {
  const float* query  = (const float*)d_in[0];
  const float* memory = (const float*)d_in[1];
  const float* Wq = (const float*)d_in[2];
  const float* bq = (const float*)d_in[3];
  const float* Wk = (const float*)d_in[4];
  const float* bk = (const float*)d_in[5];
  const float* Wv = (const float*)d_in[6];
  const float* bv = (const float*)d_in[7];
  const float* Wo = (const float*)d_in[8];
  const float* bo = (const float*)d_in[9];
  float* out = (float*)d_out;

  float*  Qp  = (float*)d_ws;                            //  4 MB
  float*  Kp  = Qp + (size_t)B_ * D_;                    // 64 MB
  float*  Vp  = Kp + (size_t)M_ * D_;                    // 64 MB
  int*    tki = (int*)(Vp + (size_t)M_ * D_);            //  8 MB
  ushort* Qbf = (ushort*)(tki + (size_t)B_ * H_ * 256);  //  2 MB
  ushort* Kbf = Qbf + (size_t)H_ * B_ * 128;             // 32 MB
  uint32_t* tkp = (uint32_t*)Vp;                 // dead until V-proj
  float*  att = (float*)Kbf;                     // 4 MB (Kbf dead post-scores)
  ushort* w1v = Kbf + (size_t)2 * 1024 * 1024;   // 0.5 MB (Kbf region)

  gemm_nt_bias64<<<dim3(B_ / 64, 4), 256, 0, stream>>>(query, Wq, bq, Qp, B_, Qbf);
  gemm_nt_bias<<<dim3(M_ / 128, 4), 256, 0, stream>>>(memory, Wk, bk, Kp, M_, Kbf);

  scores_topk_ll<<<dim3(2048), 256, 0, stream>>>(Qbf, Kbf, tkp);
  topk_select<<<dim3(B_ * H_), 256, 0, stream>>>(tkp, tki);

  convert_w1<<<dim3(256), 256, 0, stream>>>(Wv, w1v);
  gemm_bf16_nt<<<dim3(M_ / 128, 4), 256, 0, stream>>>(memory, w1v, bv, Vp, M_);

  rescore_attend<<<dim3(B_ * H_), 256, 0, stream>>>(Qp, Kp, Vp, tki, att);

  gemm_nt_bias64<<<dim3(B_ / 64, 4), 256, 0, stream>>>(att, Wo, bo, out, B_, nullptr);
}

// Round 25
// 734.916 us; speedup vs baseline: 1.0078x; 1.0078x over previous
//
#include <hip/hip_runtime.h>
#include <hip/hip_bf16.h>
#include <stdint.h>

#define B_  2048
#define D_  512
#define M_  32768
#define H_  4
#define HD_ 128
#define K_  64
#define MS_ 8
#define SLICE_ (M_ / MS_)
#define CH_ 128
#define ROWS_ 32
#define T_  8

typedef __attribute__((ext_vector_type(8))) short short8;
typedef __attribute__((ext_vector_type(4))) float float4v;
typedef __attribute__((ext_vector_type(2))) float float2v;

__device__ __forceinline__ ushort f2bf_rne(float f) {
  union { float f; unsigned u; } c; c.f = f;
  unsigned r = (c.u + 0x7fffu + ((c.u >> 16) & 1u)) >> 16;
  return (ushort)r;
}
__device__ __forceinline__ float bf2f(ushort u) {
  union { unsigned u; float f; } c; c.u = ((unsigned)u) << 16;
  return c.f;
}
__device__ __forceinline__ uint32_t make_key(float s, int inv) {
  union { float f; unsigned u; } c; c.f = s;
  unsigned m = c.u ^ ((unsigned)(((int)c.u) >> 31) | 0x80000000u);
  return ((m >> 16) << 13) | (unsigned)inv;
}
__device__ __forceinline__ unsigned sortflip32(float s) {
  union { float f; unsigned u; } c; c.f = s;
  return c.u ^ ((unsigned)(((int)c.u) >> 31) | 0x80000000u);
}

// ---------------------------------------------------------------------------
// fp32 GEMM, BM=128 tile (K-projection).  SELECTION-CRITICAL: exact fp32
// sequential-k accumulation (R6+R19 law).  LDS double-buffer (R20).
// R25: Bs half-fragment layout [16][140] (half0 @ tx*4, half1 @ 68+tx*4) —
// the old [16][132] layout's b-reads were a 4-way bank conflict (16 tx at
// 32B stride -> quads {0,2,4,6}); new layout gives 16 consecutive quads
// (2-way = free).  Row stride 140 keeps 4-row write steps bank-spread.
// Bit-identical numerics (same fmaf order per output).
// ---------------------------------------------------------------------------
__global__ __launch_bounds__(256) void gemm_nt_bias(
    const float* __restrict__ X, const float* __restrict__ W,
    const float* __restrict__ bias, float* __restrict__ C, int N,
    ushort* __restrict__ Cbf) {
  __shared__ __align__(16) float As[2][16][132];
  __shared__ __align__(16) float Bs[2][16][140];
  const int t  = threadIdx.x;
  const int tx = t & 15, ty = t >> 4;
  const int rowbase = blockIdx.x * 128;
  const int colbase = blockIdx.y * 128;
  float2v acc2[8][4];
  #pragma unroll
  for (int i = 0; i < 8; ++i)
    #pragma unroll
    for (int j = 0; j < 4; ++j) acc2[i][j] = (float2v){0.f, 0.f};

  float4 va[2], vw[2];
  auto gload = [&](int k0) {
    #pragma unroll
    for (int i = 0; i < 2; ++i) {
      int idx = t + i * 256;
      int r = idx >> 2, kq = idx & 3;
      va[i] = *(const float4*)&X[(size_t)(rowbase + r) * 512 + k0 + kq * 4];
      vw[i] = *(const float4*)&W[(size_t)(colbase + r) * 512 + k0 + kq * 4];
    }
  };
  auto sstore = [&](int buf) {
    #pragma unroll
    for (int i = 0; i < 2; ++i) {
      int idx = t + i * 256;
      int r = idx >> 2, kq = idx & 3;
      As[buf][kq*4+0][r] = va[i].x; As[buf][kq*4+1][r] = va[i].y;
      As[buf][kq*4+2][r] = va[i].z; As[buf][kq*4+3][r] = va[i].w;
      const int bo = ((r & 7) >> 2) * 68 + ((r >> 3) << 2) + (r & 3);
      Bs[buf][kq*4+0][bo] = vw[i].x; Bs[buf][kq*4+1][bo] = vw[i].y;
      Bs[buf][kq*4+2][bo] = vw[i].z; Bs[buf][kq*4+3][bo] = vw[i].w;
    }
  };

  gload(0);
  sstore(0);
  __syncthreads();
  for (int k0 = 0; k0 < 512; k0 += 16) {
    const int cur = (k0 >> 4) & 1;
    const bool more = (k0 + 16) < 512;
    if (more) gload(k0 + 16);
    #pragma unroll
    for (int k = 0; k < 16; ++k) {
      float a[8], b[8];
      *(float4*)&a[0] = *(const float4*)&As[cur][k][ty*8];
      *(float4*)&a[4] = *(const float4*)&As[cur][k][ty*8+4];
      *(float4*)&b[0] = *(const float4*)&Bs[cur][k][tx*4];
      *(float4*)&b[4] = *(const float4*)&Bs[cur][k][68 + tx*4];
      const float2v* a2 = (const float2v*)a;
      const float2v* b2 = (const float2v*)b;
      #pragma unroll
      for (int i2 = 0; i2 < 4; ++i2) {
        #pragma unroll
        for (int j = 0; j < 4; ++j) {
          asm("v_pk_fma_f32 %0, %1, %2, %0 op_sel:[0,0,0] op_sel_hi:[0,1,1]"
              : "+v"(acc2[2*i2][j]) : "v"(a2[i2]), "v"(b2[j]));
          asm("v_pk_fma_f32 %0, %1, %2, %0 op_sel:[1,0,0] op_sel_hi:[1,1,1]"
              : "+v"(acc2[2*i2+1][j]) : "v"(a2[i2]), "v"(b2[j]));
        }
      }
    }
    if (more) sstore(cur ^ 1);
    __syncthreads();
  }
  const int hh = colbase >> 7;
  #pragma unroll
  for (int i = 0; i < 8; ++i) {
    size_t r = (size_t)(rowbase + ty*8 + i);
    #pragma unroll
    for (int j4 = 0; j4 < 2; ++j4) {
      int c = colbase + tx*8 + j4*4;
      float4 bv = *(const float4*)&bias[c];
      float4 o;
      o.x = acc2[i][j4*2+0][0] + bv.x;
      o.y = acc2[i][j4*2+0][1] + bv.y;
      o.z = acc2[i][j4*2+1][0] + bv.z;
      o.w = acc2[i][j4*2+1][1] + bv.w;
      *(float4*)&C[r * 512 + c] = o;
      if (Cbf) {
        ushort u[4] __attribute__((aligned(8)));
        u[0] = f2bf_rne(o.x); u[1] = f2bf_rne(o.y);
        u[2] = f2bf_rne(o.z); u[3] = f2bf_rne(o.w);
        const int dd = tx * 8 + j4 * 4;
        *(ushort4*)&Cbf[((size_t)hh * N + r) * 128 + dd] = *(ushort4*)u;
      }
    }
  }
}

// ---------------------------------------------------------------------------
// fp32 GEMM, BM=64 tile — B_-row projections (Q, out).  fp32 (R6).
// R25: same Bs half-fragment layout as the 128-tile kernel.
// ---------------------------------------------------------------------------
__global__ __launch_bounds__(256) void gemm_nt_bias64(
    const float* __restrict__ X, const float* __restrict__ W,
    const float* __restrict__ bias, float* __restrict__ C, int N,
    ushort* __restrict__ Cbf) {
  __shared__ __align__(16) float As[16][68];
  __shared__ __align__(16) float Bs[16][140];
  const int t  = threadIdx.x;
  const int tx = t & 15, ty = t >> 4;
  const int rowbase = blockIdx.x * 64;
  const int colbase = blockIdx.y * 128;
  float acc[4][8];
  #pragma unroll
  for (int i = 0; i < 4; ++i)
    #pragma unroll
    for (int j = 0; j < 8; ++j) acc[i][j] = 0.f;

  float4 va, vw[2];
  auto gload = [&](int k0) {
    { int r = t >> 2, kq = t & 3;
      va = *(const float4*)&X[(size_t)(rowbase + r) * 512 + k0 + kq * 4]; }
    #pragma unroll
    for (int i = 0; i < 2; ++i) {
      int idx = t + i * 256;
      int r = idx >> 2, kq = idx & 3;
      vw[i] = *(const float4*)&W[(size_t)(colbase + r) * 512 + k0 + kq * 4];
    }
  };
  auto sstore = [&]() {
    { int r = t >> 2, kq = t & 3;
      As[kq*4+0][r] = va.x; As[kq*4+1][r] = va.y;
      As[kq*4+2][r] = va.z; As[kq*4+3][r] = va.w; }
    #pragma unroll
    for (int i = 0; i < 2; ++i) {
      int idx = t + i * 256;
      int r = idx >> 2, kq = idx & 3;
      const int bo = ((r & 7) >> 2) * 68 + ((r >> 3) << 2) + (r & 3);
      Bs[kq*4+0][bo] = vw[i].x; Bs[kq*4+1][bo] = vw[i].y;
      Bs[kq*4+2][bo] = vw[i].z; Bs[kq*4+3][bo] = vw[i].w;
    }
  };

  gload(0);
  for (int k0 = 0; k0 < 512; k0 += 16) {
    sstore();
    __syncthreads();
    if (k0 + 16 < 512) gload(k0 + 16);
    #pragma unroll
    for (int k = 0; k < 16; ++k) {
      float a[4], b[8];
      *(float4*)&a[0] = *(const float4*)&As[k][ty*4];
      *(float4*)&b[0] = *(const float4*)&Bs[k][tx*4];
      *(float4*)&b[4] = *(const float4*)&Bs[k][68 + tx*4];
      #pragma unroll
      for (int i = 0; i < 4; ++i)
        #pragma unroll
        for (int j = 0; j < 8; ++j)
          acc[i][j] = fmaf(a[i], b[j], acc[i][j]);
    }
    __syncthreads();
  }
  const int hh = colbase >> 7;
  #pragma unroll
  for (int i = 0; i < 4; ++i) {
    size_t r = (size_t)(rowbase + ty*4 + i);
    #pragma unroll
    for (int j4 = 0; j4 < 2; ++j4) {
      int c = colbase + tx*8 + j4*4;
      float4 bv = *(const float4*)&bias[c];
      float4 o;
      o.x = acc[i][j4*4+0] + bv.x;
      o.y = acc[i][j4*4+1] + bv.y;
      o.z = acc[i][j4*4+2] + bv.z;
      o.w = acc[i][j4*4+3] + bv.w;
      *(float4*)&C[r * 512 + c] = o;
      if (Cbf) {
        ushort u[4] __attribute__((aligned(8)));
        u[0] = f2bf_rne(o.x); u[1] = f2bf_rne(o.y);
        u[2] = f2bf_rne(o.z); u[3] = f2bf_rne(o.w);
        const int dd = tx * 8 + j4 * 4;
        *(ushort4*)&Cbf[((size_t)hh * N + r) * 128 + dd] = *(ushort4*)u;
      }
    }
  }
}

// ---------------------------------------------------------------------------
// Convert fp32 weight -> bf16 (single, RNE).  V projection only.
// ---------------------------------------------------------------------------
__global__ __launch_bounds__(256) void convert_w1(
    const float* __restrict__ W, ushort* __restrict__ W1) {
  const int i = (blockIdx.x * 256 + threadIdx.x) * 4;
  float4 v = *(const float4*)&W[i];
  ushort u1[4] __attribute__((aligned(8)));
  u1[0] = f2bf_rne(v.x); u1[1] = f2bf_rne(v.y);
  u1[2] = f2bf_rne(v.z); u1[3] = f2bf_rne(v.w);
  *(ushort4*)&W1[i] = *(ushort4*)u1;
}

// ---------------------------------------------------------------------------
// Single-bf16 MFMA GEMM — V projection (R22; V enters output linearly).
// ---------------------------------------------------------------------------
__global__ __launch_bounds__(256, 4) void gemm_bf16_nt(
    const float* __restrict__ X, const ushort* __restrict__ W1,
    const float* __restrict__ bias, float* __restrict__ C, int N) {
  const int t = threadIdx.x, w = t >> 6, lane = t & 63;
  const int l15 = lane & 15, l4 = lane >> 4;
  const int nb = blockIdx.x * 128 + w * 32;
  const int ob = blockIdx.y * 128;
  const short* w1s = (const short*)W1;

  float4v acc[2][8];
  #pragma unroll
  for (int nt = 0; nt < 2; ++nt)
    #pragma unroll
    for (int ot = 0; ot < 8; ++ot) acc[nt][ot] = (float4v){0.f, 0.f, 0.f, 0.f};

  for (int ks = 0; ks < 16; ++ks) {
    short8 x1[2];
    #pragma unroll
    for (int nt = 0; nt < 2; ++nt) {
      const float* xp = X + (size_t)(nb + nt * 16 + l15) * 512 + ks * 32 + l4 * 8;
      float xv[8];
      *(float4*)&xv[0] = *(const float4*)xp;
      *(float4*)&xv[4] = *(const float4*)(xp + 4);
      #pragma unroll
      for (int j = 0; j < 8; ++j)
        ((ushort*)&x1[nt])[j] = f2bf_rne(xv[j]);
    }
    #pragma unroll
    for (int ot = 0; ot < 8; ++ot) {
      const size_t wo = (size_t)(ob + ot * 16 + l15) * 512 + ks * 32 + l4 * 8;
      short8 wf1 = *(const short8*)(w1s + wo);
      #pragma unroll
      for (int nt = 0; nt < 2; ++nt)
        acc[nt][ot] = __builtin_amdgcn_mfma_f32_16x16x32_bf16(wf1, x1[nt], acc[nt][ot], 0, 0, 0);
    }
  }

  #pragma unroll
  for (int nt = 0; nt < 2; ++nt) {
    const size_t row = (size_t)(nb + nt * 16 + l15);
    #pragma unroll
    for (int ot = 0; ot < 8; ++ot) {
      const int col = ob + ot * 16 + l4 * 4;
      float4 bv = *(const float4*)&bias[col];
      float4 o;
      o.x = acc[nt][ot][0] + bv.x;
      o.y = acc[nt][ot][1] + bv.y;
      o.z = acc[nt][ot][2] + bv.z;
      o.w = acc[nt][ot][3] + bv.w;
      *(float4*)&C[row * 512 + col] = o;
    }
  }
}

// ---------------------------------------------------------------------------
// Pass 1: bf16 MFMA scores + selection, asm-pipelined K loads (R18 1-deep;
// R24's 2-deep was time-identical at higher VGPR, reverted).
// ---------------------------------------------------------------------------
__global__ __launch_bounds__(256, 3) void scores_topk_ll(
    const ushort* __restrict__ Qbf, const ushort* __restrict__ Kbf,
    uint32_t* __restrict__ tkp) {
  const int t = threadIdx.x, w = t >> 6, lane = t & 63;
  const int l   = blockIdx.x;
  const int xcd = l & 7;
  const int i2  = l >> 3;
  const int s   = xcd + 8 * (i2 >> 6);
  const int h   = s >> 3, z = s & 7;
  const int rowbase = (i2 & 63) * ROWS_;
  const int mbase = z * SLICE_;
  const int l15 = lane & 15, l4 = lane >> 4;

  short8 qf0[4], qf1[4];
  {
    const short* Q0 = (const short*)Qbf +
        ((size_t)h * B_ + rowbase + l15) * 128 + l4 * 8;
    const short* Q1 = (const short*)Qbf +
        ((size_t)h * B_ + rowbase + 16 + l15) * 128 + l4 * 8;
    #pragma unroll
    for (int ks = 0; ks < 4; ++ks) {
      qf0[ks] = *(const short8*)(Q0 + ks * 32);
      qf1[ks] = *(const short8*)(Q1 + ks * 32);
    }
  }

  const short* Kh = (const short*)Kbf + (size_t)h * M_ * 128;

  uint32_t kt0[T_], kt1[T_];
  #pragma unroll
  for (int j = 0; j < T_; ++j) { kt0[j] = 0u; kt1[j] = 0u; }

  auto ins = [&](uint32_t c, uint32_t* kt) {
    uint32_t prev = kt[0];
    kt[0] = (kt[0] >= c) ? kt[0] : c;
    #pragma unroll
    for (int i = 1; i < T_; ++i) {
      uint32_t cur = kt[i];
      uint32_t nv;
      asm("v_med3_u32 %0, %1, %2, %3" : "=v"(nv) : "v"(prev), "v"(cur), "v"(c));
      kt[i] = nv;
      prev = cur;
    }
  };

  uint64_t adr[8];
  #pragma unroll
  for (int tt = 0; tt < 2; ++tt)
    #pragma unroll
    for (int ks = 0; ks < 4; ++ks)
      adr[tt * 4 + ks] = (uint64_t)(Kh +
          (size_t)(mbase + 32 * w + 16 * tt + l15) * 128 + ks * 32 + l4 * 8);

  short8 bufA[8], bufB[8];
  auto issue = [&](short8 (&buf)[8]) {
    #pragma unroll
    for (int i = 0; i < 8; ++i) {
      asm volatile("global_load_dwordx4 %0, %1, off"
                   : "=&v"(buf[i]) : "v"(adr[i]));
      adr[i] += (uint64_t)(CH_ * 128 * 2);
    }
  };
  auto compute = [&](int ch, short8 (&buf)[8]) {
    #pragma unroll
    for (int tt = 0; tt < 2; ++tt) {
      const int inv0 = SLICE_ - 1 - (ch * CH_ + 32 * w + 16 * tt + 4 * l4);
      float4v a0 = {0.f, 0.f, 0.f, 0.f};
      float4v a1 = {0.f, 0.f, 0.f, 0.f};
      #pragma unroll
      for (int ks = 0; ks < 4; ++ks) {
        a0 = __builtin_amdgcn_mfma_f32_16x16x32_bf16(buf[tt * 4 + ks], qf0[ks], a0, 0, 0, 0);
        a1 = __builtin_amdgcn_mfma_f32_16x16x32_bf16(buf[tt * 4 + ks], qf1[ks], a1, 0, 0, 0);
      }
      #pragma unroll
      for (int reg = 0; reg < 4; ++reg) ins(make_key(a0[reg], inv0 - reg), kt0);
      #pragma unroll
      for (int reg = 0; reg < 4; ++reg) ins(make_key(a1[reg], inv0 - reg), kt1);
    }
  };

  const int NCH = SLICE_ / CH_;
  issue(bufA);
  for (int ch = 0; ch < NCH; ch += 2) {
    issue(bufB);
    asm volatile("s_waitcnt vmcnt(8)" ::: "memory");
    __builtin_amdgcn_sched_barrier(0);
    compute(ch, bufA);
    if (ch + 2 < NCH) {
      issue(bufA);
      asm volatile("s_waitcnt vmcnt(8)" ::: "memory");
    } else {
      asm volatile("s_waitcnt vmcnt(0)" ::: "memory");
    }
    __builtin_amdgcn_sched_barrier(0);
    compute(ch + 1, bufB);
  }

  const int id = w * 4 + l4;
  const size_t base0 =
      ((((size_t)(rowbase + l15)) * H_ + h) * MS_ + z) * (16 * T_) + (size_t)id * T_;
  const size_t base1 =
      ((((size_t)(rowbase + 16 + l15)) * H_ + h) * MS_ + z) * (16 * T_) + (size_t)id * T_;
  #pragma unroll
  for (int j = 0; j < T_; ++j) {
    tkp[base0 + j] = kt0[j];
    tkp[base1 + j] = kt1[j];
  }
}

// ---------------------------------------------------------------------------
// Merge: per (b,h), 1024 pooled keys -> threshold set (theta with -(1<<16)
// margin), compacted indices into tki.  Runs before V-proj clobbers tkp.
// ---------------------------------------------------------------------------
__global__ __launch_bounds__(256) void topk_select(
    const uint32_t* __restrict__ tkp, int* __restrict__ tki) {
  __shared__ unsigned h1[256];
  __shared__ unsigned h2[256];
  __shared__ unsigned bstar, cstar, nabove;
  __shared__ int ocnt;
  __shared__ int outi[256];
  const int t = threadIdx.x;
  const int bh = blockIdx.x;
  const uint32_t* src = tkp + (size_t)bh * (MS_ * 16 * T_);
  uint32_t k[4];
  #pragma unroll
  for (int j = 0; j < 4; ++j) k[j] = src[j * 256 + t];
  h1[t] = 0; h2[t] = 0;
  if (t == 0) ocnt = 0;
  __syncthreads();
  #pragma unroll
  for (int j = 0; j < 4; ++j) atomicAdd(&h1[k[j] >> 24], 1u);
  __syncthreads();
  unsigned v = h1[t];
  for (int d = 1; d < 256; d <<= 1) {
    unsigned o = (t + d < 256) ? h1[t + d] : 0u;
    __syncthreads();
    v += o; h1[t] = v;
    __syncthreads();
  }
  if (h1[t] >= 64u && (t == 255 || h1[t + 1] < 64u)) {
    bstar = (unsigned)t; nabove = (t == 255) ? 0u : h1[t + 1];
  }
  __syncthreads();
  const unsigned bs = bstar, na = nabove;
  #pragma unroll
  for (int j = 0; j < 4; ++j)
    if ((k[j] >> 24) == bs) atomicAdd(&h2[(k[j] >> 16) & 0xFFu], 1u);
  __syncthreads();
  v = h2[t];
  for (int d = 1; d < 256; d <<= 1) {
    unsigned o = (t + d < 256) ? h2[t + d] : 0u;
    __syncthreads();
    v += o; h2[t] = v;
    __syncthreads();
  }
  if (na + h2[t] >= 64u && (t == 255 || na + h2[t + 1] < 64u)) cstar = (unsigned)t;
  __syncthreads();
  const uint32_t theta = ((((bs << 8) | cstar) << 16)) - 65536u;
  #pragma unroll
  for (int j = 0; j < 4; ++j) {
    if (k[j] >= theta) {
      int p = atomicAdd(&ocnt, 1);
      if (p < 256) {
        const int pos = j * 256 + t;
        const int z = pos >> 7;
        const int ci = (SLICE_ - 1) - (int)(k[j] & 0xFFFu);
        outi[p] = (z << 12) | ci;
      }
    }
  }
  __syncthreads();
  int n = ocnt; if (n > 256) n = 256;
  if (t >= n) outi[t] = -(t + 1);
  __syncthreads();
  tki[(size_t)bh * 256 + t] = outi[t];
}

// ---------------------------------------------------------------------------
// Pass 2: exact fp32 rescore (padded slots skip gathers) + rank-based exact
// top-64 + softmax + V-gather.
// ---------------------------------------------------------------------------
__global__ __launch_bounds__(256) void rescore_attend(
    const float* __restrict__ Qp, const float* __restrict__ Kp,
    const float* __restrict__ Vp, const int* __restrict__ tki,
    float* __restrict__ att) {
  __shared__ float q_[128];
  __shared__ float s_[256];
  __shared__ int   i_[256];
  __shared__ unsigned long long sk_[256];
  __shared__ float wsm[64];
  __shared__ int   widx[64];
  __shared__ float smax_s;
  const int bh = blockIdx.x, b = bh >> 2, h = bh & 3;
  const int t = threadIdx.x, w = t >> 6, lane = t & 63;
  const float SCALE = 0.08838834764831843f;

  if (t < 32) *(float4*)&q_[t * 4] = *(const float4*)&Qp[(size_t)b * 512 + h * 128 + t * 4];
  i_[t] = tki[(size_t)bh * 256 + t];
  __syncthreads();

  const int o = lane >> 3, il = lane & 7;
  #pragma unroll 2
  for (int p = 0; p < 8; ++p) {
    const int j = w * 64 + p * 8 + o;
    const int idx = i_[j];
    if (idx >= 0) {
      const float* kr = Kp + (size_t)idx * 512 + h * 128;
      float part = 0.f;
      #pragma unroll
      for (int u = 0; u < 4; ++u) {
        const int f = il + u * 8;
        float4 kv = *(const float4*)&kr[f * 4];
        float4 qv = *(const float4*)&q_[f * 4];
        part += kv.x * qv.x + kv.y * qv.y + kv.z * qv.z + kv.w * qv.w;
      }
      part += __shfl_xor(part, 1);
      part += __shfl_xor(part, 2);
      part += __shfl_xor(part, 4);
      if (il == 0) s_[j] = part * SCALE;
    } else {
      if (il == 0) s_[j] = -3.0e38f;
    }
  }
  __syncthreads();

  sk_[t] = ((unsigned long long)sortflip32(s_[t]) << 32) |
           (unsigned)(~(unsigned)i_[t]);
  __syncthreads();
  const unsigned long long myk = sk_[t];
  int rank = 0;
  #pragma unroll 8
  for (int j = 0; j < 256; ++j) rank += (sk_[j] > myk) ? 1 : 0;
  const bool sel = (rank < 64);
  if (rank == 0) smax_s = s_[t];
  __syncthreads();
  if (sel) {
    wsm[rank]  = expf(s_[t] - smax_s);
    widx[rank] = i_[t];
  }
  __syncthreads();
  if (t < 64) {
    float zz = wsm[t];
    #pragma unroll
    for (int off = 32; off; off >>= 1) zz += __shfl_xor(zz, off);
    wsm[t] = wsm[t] / zz;
  }
  __syncthreads();

  if (t < 128) {
    float a = 0.f;
    #pragma unroll 4
    for (int k2 = 0; k2 < 64; ++k2)
      a = fmaf(wsm[k2], Vp[(size_t)widx[k2] * 512 + h * 128 + t], a);
    att[(size_t)b * 512 + h * 128 + t] = a;
  }
}

// ---------------------------------------------------------------------------
extern "C" void kernel_launch(void* const* d_in, const int* in_sizes, int n_in,
                              void* d_out, int out_size, void* d_ws, size_t ws_size,
                              hipStream_t stream) {
  const float* query  = (const float*)d_in[0];
  const float* memory = (const float*)d_in[1];
  const float* Wq = (const float*)d_in[2];
  const float* bq = (const float*)d_in[3];
  const float* Wk = (const float*)d_in[4];
  const float* bk = (const float*)d_in[5];
  const float* Wv = (const float*)d_in[6];
  const float* bv = (const float*)d_in[7];
  const float* Wo = (const float*)d_in[8];
  const float* bo = (const float*)d_in[9];
  float* out = (float*)d_out;

  float*  Qp  = (float*)d_ws;                            //  4 MB
  float*  Kp  = Qp + (size_t)B_ * D_;                    // 64 MB
  float*  Vp  = Kp + (size_t)M_ * D_;                    // 64 MB
  int*    tki = (int*)(Vp + (size_t)M_ * D_);            //  8 MB
  ushort* Qbf = (ushort*)(tki + (size_t)B_ * H_ * 256);  //  2 MB
  ushort* Kbf = Qbf + (size_t)H_ * B_ * 128;             // 32 MB
  uint32_t* tkp = (uint32_t*)Vp;                 // dead until V-proj
  float*  att = (float*)Kbf;                     // 4 MB (Kbf dead post-scores)
  ushort* w1v = Kbf + (size_t)2 * 1024 * 1024;   // 0.5 MB (Kbf region)

  gemm_nt_bias64<<<dim3(B_ / 64, 4), 256, 0, stream>>>(query, Wq, bq, Qp, B_, Qbf);
  gemm_nt_bias<<<dim3(M_ / 128, 4), 256, 0, stream>>>(memory, Wk, bk, Kp, M_, Kbf);

  scores_topk_ll<<<dim3(2048), 256, 0, stream>>>(Qbf, Kbf, tkp);
  topk_select<<<dim3(B_ * H_), 256, 0, stream>>>(tkp, tki);

  convert_w1<<<dim3(256), 256, 0, stream>>>(Wv, w1v);
  gemm_bf16_nt<<<dim3(M_ / 128, 4), 256, 0, stream>>>(memory, w1v, bv, Vp, M_);

  rescore_attend<<<dim3(B_ * H_), 256, 0, stream>>>(Qp, Kp, Vp, tki, att);

  gemm_nt_bias64<<<dim3(B_ / 64, 4), 256, 0, stream>>>(att, Wo, bo, out, B_, nullptr);
}